// Round 3
// baseline (136.629 us; speedup 1.0000x reference)
//
#include <hip/hip_runtime.h>

// ---------------------------------------------------------------------------
// ConvQuantizationWrapper: exact integer reformulation, MFMA i8, fully fused.
// out = [conv3x3(q_in, tc(q_w)) + zp*conv3x3(ones, q_w)] / (sa*sw) + bias
//   q_in = clip(round(x*sa - zp), 0, 255) (u8);  q_w = round(w*sw)
//
// R7: A/B evidence across R0-R2 (three structurally different pipelines all
// ~126us, our kernels never in top-5, top-5 = fixed 256MiB harness fills at
// 80% HBM) => timed window ~= ~92us fixed fills + ~33us our kernels; floor
// ~= 103MB mandatory traffic ~= 20us. This round attacks the ~12us gap:
//  1. XCD swizzle: g=(b&7)*112+b>>3 -> each XCD owns 8 whole images; blocks
//     sharing halo rows co-locate on one XCD's L2 (halo re-reads were
//     cross-XCD L3 round-trips).
//  2. v_cvt_pk_u8_f32 (clamp+cvt+byte-insert in 1 op; input integral after
//     rintf so truncation exact, saturation == clip) cuts phase-1 quant from
//     ~9 to ~4.25 VALU ops/value.
//  3. Non-temporal out stores: stop 51MB of writes evicting x halo from L2.
//  4. Phase-1 unroll 2->3: more loads in flight.
// ---------------------------------------------------------------------------

typedef int v4i __attribute__((ext_vector_type(4)));
typedef float v4f __attribute__((ext_vector_type(4)));

#define ROWB 80   // LDS bytes per qa (row,col) entry: 64 data + 16 pad

// ---- fused weight prep: quantize + 9-case border-correction table ----
__global__ __launch_bounds__(64) void prep_wq(const float* __restrict__ wt,
                                              const float* __restrict__ sw_p,
                                              const float* __restrict__ zp_p,
                                              signed char* __restrict__ w8,
                                              float* __restrict__ corr_tab) {
  const int o = blockIdx.x;             // 0..63
  const int i = threadIdx.x;            // input channel 0..63
  const float sw = sw_p[0];
  const float* wp = wt + (size_t)(o * 64 + i) * 9;
  int q[9];
#pragma unroll
  for (int k = 0; k < 9; ++k) q[k] = (int)rintf(wp[k] * sw);
#pragma unroll
  for (int k = 0; k < 9; ++k)
    w8[(o * 9 + k) * 64 + i] = (signed char)(q[k] & 255);

  int stc[9], srw[9];
#pragma unroll
  for (int k = 0; k < 9; ++k) {
    int a = (int)(signed char)(q[k] & 255);   // two's-complement i8 value
    int b = q[k];
#pragma unroll
    for (int off = 32; off; off >>= 1) {      // xor butterfly: sum in ALL lanes
      a += __shfl_xor(a, off);
      b += __shfl_xor(b, off);
    }
    stc[k] = a; srw[k] = b;
  }
  const float zp = zp_p[0];
  if (i < 9) {                          // lane i computes border case i
    const int v = i / 3, hc = i % 3;
    float corr = 0.0f;
#pragma unroll
    for (int k = 0; k < 9; ++k) {
      const int kh = k / 3, kw = k % 3;
      const bool drop = (v == 1 && kh == 0) || (v == 2 && kh == 2) ||
                        (hc == 1 && kw == 0) || (hc == 2 && kw == 2);
      if (!drop) corr += 128.0f * (float)stc[k] + zp * (float)srw[k];
    }
    corr_tab[i * 64 + o] = corr;
  }
}

// ---- fused quantize + conv: LDS-staged implicit GEMM on mfma_i32_16x16x64 ----
// grid 896 (1D, XCD-swizzled): block = one n, 4 output rows, all 64 och.
// Phase 1: 1536 tasks. idx -> cg = idx&15 (channel group of 4), rem = idx>>4,
// row = rem/14 (qa row 0..5), w4 = rem%14 (pixel quad). Lane order cg-fastest
// + rem-per-quarter => 16 fully-used 64B lines per wave load instr.
// Phase 2: 4 waves = (px-half) x (och-pair); 7 M-tiles of 16 px each; per
// tile 9 ds_read_b128 A-frags, each feeding 2 MFMAs (och oa, oa+16).
__global__ __launch_bounds__(256, 4) void conv_fused(
    const float* __restrict__ x, const signed char* __restrict__ w8,
    const float* __restrict__ corr_tab, const float* __restrict__ bias,
    const float* __restrict__ sa_p, const float* __restrict__ sw_p,
    const float* __restrict__ zp_p, float* __restrict__ out) {
  __shared__ __align__(16) signed char lds[6 * 58 * ROWB];   // 27,840 B
  const int tid = threadIdx.x;
  // XCD swizzle: 896 = 8 xcd * 112; contiguous 112 work-items (8 images) per
  // XCD so halo-sharing neighbor blocks hit the same L2.
  const int b = blockIdx.x;
  const int g = (b & 7) * 112 + (b >> 3);
  const int n = (g * 2341) >> 15;       // g / 14 (exact for g < 896)
  const int h0 = (g - n * 14) * 4;      // output rows h0..h0+3
  const float sa = sa_p[0], zp = zp_p[0];
  const float* xim = x + (size_t)n * 200704;    // 64 * 3136

  // ---- phase 1: quantize 6 padded rows directly into LDS ----
#pragma unroll 3
  for (int it = 0; it < 6; ++it) {
    const int idx = tid + 256 * it;     // 0..1535
    if (idx < 1344) {                   // quant tasks
      const int cg = idx & 15;
      const int rem = idx >> 4;         // 0..83
      const int row = (rem * 2341) >> 15;   // rem / 14 (exact)
      const int w4 = rem - row * 14;
      const int ih = h0 - 1 + row;
      const bool valid = (unsigned)ih < 56u;
      int* const dst = (int*)lds + (row * 58 + w4 * 4 + 1) * (ROWB / 4) + cg;
      if (valid) {
        v4f v[4];
#pragma unroll
        for (int j = 0; j < 4; ++j)
          v[j] = *(const v4f*)(xim + (size_t)(cg * 4 + j) * 3136 + ih * 56 + w4 * 4);
#pragma unroll
        for (int e = 0; e < 4; ++e) {
          float qf[4];
#pragma unroll
          for (int j = 0; j < 4; ++j) {
            float tq;
            {
#pragma clang fp contract(off)
              tq = v[j][e] * sa - zp;   // match ref: mul then sub, no fma
            }
            qf[j] = rintf(tq);          // half-to-even, like jnp.round
          }
          // v_cvt_pk_u8_f32: u8-saturate (== clip 0..255; input integral so
          // truncation exact) + insert into byte j, other bytes pass through.
          unsigned dw;
          asm("v_cvt_pk_u8_f32 %0, %1, 0, %2" : "=v"(dw) : "v"(qf[0]), "v"(0u));
          asm("v_cvt_pk_u8_f32 %0, %1, 1, %2" : "=v"(dw) : "v"(qf[1]), "v"(dw));
          asm("v_cvt_pk_u8_f32 %0, %1, 2, %2" : "=v"(dw) : "v"(qf[2]), "v"(dw));
          asm("v_cvt_pk_u8_f32 %0, %1, 3, %2" : "=v"(dw) : "v"(qf[3]), "v"(dw));
          dst[e * (ROWB / 4)] = (int)(dw ^ 0x80808080u);   // (q - 128) bytes
        }
      } else {
#pragma unroll
        for (int e = 0; e < 4; ++e) dst[e * (ROWB / 4)] = 0;
      }
    } else {                            // col pads: col 0 and col 57, 6 rows
      const int z = idx - 1344;         // 0..191
      const int loc = z >> 4, d = z & 15;
      const int row = loc >> 1, side = loc & 1;
      ((int*)lds)[(row * 58 + side * 57) * (ROWB / 4) + d] = 0;
    }
  }
  __syncthreads();

  // ---- phase 2: MFMA implicit GEMM ----
  const int lane = tid & 63;
  const int wv = tid >> 6;
  const int phalf = wv & 1;             // px offset 112*phalf
  const int ogp = wv >> 1;              // och 32*ogp
  const int ln = lane & 15;
  const int kg = lane >> 4;             // k-group: bytes kg*16..kg*16+15
  const int oa = ogp * 32 + ln;         // first och; second is oa+16

  // B fragments for both och groups: B[n=ln][k = kg*16 + j] per tap
  const signed char* wba = w8 + (size_t)oa * 576 + kg * 16;
  v4i Ba[9], Bb[9];
#pragma unroll
  for (int t = 0; t < 9; ++t) {
    Ba[t] = *(const v4i*)(wba + t * 64);
    Bb[t] = *(const v4i*)(wba + 9216 + t * 64);   // (oa+16)*576
  }

  const float sw = sw_p[0];
  const float rden = 1.0f / (sw * sa);
  const float boa = bias[oa], bob = bias[oa + 16];
  const float cFa = corr_tab[oa];       // interior (case 0) corrections (L2)
  const float cFb = corr_tab[oa + 16];
  float* const outa = out + (size_t)(n * 64 + oa) * 3136 + h0 * 56;
  float* const outb = outa + 16 * 3136;

#pragma unroll 1
  for (int t = 0; t < 7; ++t) {
    const int pb = phalf * 112 + t * 16;          // block-relative px tile base
    const int pa = pb + ln;                       // this lane's A-row px (0..223)
    const int hr = (pa * 9363) >> 19;             // pa / 56 (exact)
    const int wc = pa - hr * 56;
    const signed char* ab = lds + (hr * 58 + wc) * ROWB + kg * 16;
    v4i acca = {0, 0, 0, 0}, accb = {0, 0, 0, 0};
#pragma unroll
    for (int kh = 0; kh < 3; ++kh) {
#pragma unroll
      for (int kw = 0; kw < 3; ++kw) {
        const v4i A = *(const v4i*)(ab + (kh * 58 + kw) * ROWB);
        acca = __builtin_amdgcn_mfma_i32_16x16x64_i8(A, Ba[kh * 3 + kw], acca, 0, 0, 0);
        accb = __builtin_amdgcn_mfma_i32_16x16x64_i8(A, Bb[kh * 3 + kw], accb, 0, 0, 0);
      }
    }
    // epilogue: C/D row(px) = kg*4 + reg, col(och) = ln
    const int pxb = pb + kg * 4;
    float ta[4], tb[4];
#pragma unroll
    for (int e = 0; e < 4; ++e) {
      const int px = pxb + e;
      const int hh = (px * 9363) >> 19;
      const int ww = px - hh * 56;
      const int hg = h0 + hh;
      float ca = cFa, cb = cFb;
      if ((hg == 0) | (hg == 55) | (ww == 0) | (ww == 55)) {   // rare border
        const int vcase = (hg == 0) ? 1 : ((hg == 55) ? 2 : 0);
        const int hcase = (ww == 0) ? 1 : ((ww == 55) ? 2 : 0);
        const int cidx = (vcase * 3 + hcase) * 64;
        ca = corr_tab[cidx + oa];
        cb = corr_tab[cidx + oa + 16];
      }
      ta[e] = ((float)acca[e] + ca) * rden + boa;
      tb[e] = ((float)accb[e] + cb) * rden + bob;
    }
    const v4f va = {ta[0], ta[1], ta[2], ta[3]};
    const v4f vb = {tb[0], tb[1], tb[2], tb[3]};
    __builtin_nontemporal_store(va, (v4f*)(outa + pxb));   // keep L2 for x halo
    __builtin_nontemporal_store(vb, (v4f*)(outb + pxb));
  }
}

extern "C" void kernel_launch(void* const* d_in, const int* in_sizes, int n_in,
                              void* d_out, int out_size, void* d_ws, size_t ws_size,
                              hipStream_t stream) {
  const float* x    = (const float*)d_in[0];
  const float* wt   = (const float*)d_in[1];
  const float* bias = (const float*)d_in[2];
  const float* sa   = (const float*)d_in[3];
  const float* sw   = (const float*)d_in[4];
  const float* zp   = (const float*)d_in[5];
  float* out = (float*)d_out;

  char* ws = (char*)d_ws;
  signed char* w8 = (signed char*)ws;                 // 36,864 B
  float* corr_tab = (float*)(ws + 36864);             // 2,304 B

  prep_wq<<<64, 64, 0, stream>>>(wt, sw, zp, w8, corr_tab);
  conv_fused<<<896, 256, 0, stream>>>(x, w8, corr_tab, bias, sa, sw, zp, out);
}

// Round 4
// 131.368 us; speedup vs baseline: 1.0400x; 1.0400x over previous
//
#include <hip/hip_runtime.h>

// ---------------------------------------------------------------------------
// ConvQuantizationWrapper: exact integer reformulation, MFMA i8, fully fused.
// out = [conv3x3(q_in, tc(q_w)) + zp*conv3x3(ones, q_w)] / (sa*sw) + bias
//   q_in = clip(round(x*sa - zp), 0, 255) (u8);  q_w = round(w*sw)
//
// R8: post-mortem of R3 (conv_fused 48.5us, MfmaUtil 5%, VALUBusy 13%,
// 1.04M LDS bank conflicts -> latency-bound, not BW-bound; FETCH 36MB < x
// size because x stays L3-resident across iterations):
//  1. REVERT inline-asm v_cvt_pk_u8_f32 (m240: -37% vs scalar cast; the
//     4-op serial asm chain defeats the scheduler) -> scalar clamp/cvt.
//  2. REVERT nontemporal stores (WRITE 60MB, no benefit) -> plain float4.
//  3. FIX phase-2 8-way bank conflict for real: ROWB=80 gave quad index
//     (5*ln+kg) mod 8 which covers only 2/8 quads within each 16-lane
//     quarter. Now: 16B-unit XOR swizzle — channel-unit u of column c is
//     stored at unit u ^ ((c>>1)&3). Tile bases are 0 mod 8 in c, so each
//     quarter covers all 8 bank-quads exactly twice = 2-way = free (m136).
//     Writes go 2-way -> 4-way on ~96 instr/block: negligible. LDS 22.3KB.
//  4. Keep XCD swizzle (each XCD owns 8 whole images; halo-sharing blocks
//     share one L2) and phase-1 unroll 2 (R2-known-good).
// ---------------------------------------------------------------------------

typedef int v4i __attribute__((ext_vector_type(4)));
typedef float v4f __attribute__((ext_vector_type(4)));

// ---- fused weight prep: quantize + 9-case border-correction table ----
__global__ __launch_bounds__(64) void prep_wq(const float* __restrict__ wt,
                                              const float* __restrict__ sw_p,
                                              const float* __restrict__ zp_p,
                                              signed char* __restrict__ w8,
                                              float* __restrict__ corr_tab) {
  const int o = blockIdx.x;             // 0..63
  const int i = threadIdx.x;            // input channel 0..63
  const float sw = sw_p[0];
  const float* wp = wt + (size_t)(o * 64 + i) * 9;
  int q[9];
#pragma unroll
  for (int k = 0; k < 9; ++k) q[k] = (int)rintf(wp[k] * sw);
#pragma unroll
  for (int k = 0; k < 9; ++k)
    w8[(o * 9 + k) * 64 + i] = (signed char)(q[k] & 255);

  int stc[9], srw[9];
#pragma unroll
  for (int k = 0; k < 9; ++k) {
    int a = (int)(signed char)(q[k] & 255);   // two's-complement i8 value
    int b = q[k];
#pragma unroll
    for (int off = 32; off; off >>= 1) {      // xor butterfly: sum in ALL lanes
      a += __shfl_xor(a, off);
      b += __shfl_xor(b, off);
    }
    stc[k] = a; srw[k] = b;
  }
  const float zp = zp_p[0];
  if (i < 9) {                          // lane i computes border case i
    const int v = i / 3, hc = i % 3;
    float corr = 0.0f;
#pragma unroll
    for (int k = 0; k < 9; ++k) {
      const int kh = k / 3, kw = k % 3;
      const bool drop = (v == 1 && kh == 0) || (v == 2 && kh == 2) ||
                        (hc == 1 && kw == 0) || (hc == 2 && kw == 2);
      if (!drop) corr += 128.0f * (float)stc[k] + zp * (float)srw[k];
    }
    corr_tab[i * 64 + o] = corr;
  }
}

// ---- fused quantize + conv: LDS-staged implicit GEMM on mfma_i32_16x16x64 ----
// grid 896 (1D, XCD-swizzled): block = one n, 4 output rows, all 64 och.
// qa LDS layout: group g = row*58 + col (64B = 16 dwords = 4 16B units);
// unit u (channels 16u..16u+15) lives at unit u ^ ((col>>1)&3).
// Phase 1: 1536 tasks. idx -> cg = idx&15 (channel dword), rem = idx>>4,
// row = rem/14 (qa row 0..5), w4 = rem%14 (pixel quad).
// Phase 2: 4 waves = (px-half) x (och-pair); 7 M-tiles of 16 px each; per
// tile 9 ds_read_b128 A-frags (conflict-free), each feeding 2 MFMAs.
__global__ __launch_bounds__(256, 4) void conv_fused(
    const float* __restrict__ x, const signed char* __restrict__ w8,
    const float* __restrict__ corr_tab, const float* __restrict__ bias,
    const float* __restrict__ sa_p, const float* __restrict__ sw_p,
    const float* __restrict__ zp_p, float* __restrict__ out) {
  __shared__ __align__(16) signed char lds[22272];   // 6*58 groups * 64B
  const int tid = threadIdx.x;
  // XCD swizzle: 896 = 8 xcd * 112; contiguous 112 work-items (8 images) per
  // XCD so halo-sharing neighbor blocks hit the same L2.
  const int b = blockIdx.x;
  const int g = (b & 7) * 112 + (b >> 3);
  const int n = (g * 2341) >> 15;       // g / 14 (exact for g < 896)
  const int h0 = (g - n * 14) * 4;      // output rows h0..h0+3
  const float sa = sa_p[0], zp = zp_p[0];
  const float* xim = x + (size_t)n * 200704;    // 64 * 3136

  // ---- phase 1: quantize 6 padded rows directly into LDS ----
#pragma unroll 2
  for (int it = 0; it < 6; ++it) {
    const int idx = tid + 256 * it;     // 0..1535
    if (idx < 1344) {                   // quant tasks
      const int cg = idx & 15;
      const int rem = idx >> 4;         // 0..83
      const int row = (rem * 2341) >> 15;   // rem / 14 (exact)
      const int w4 = rem - row * 14;
      const int ih = h0 - 1 + row;
      const bool valid = (unsigned)ih < 56u;
      v4f v[4];
      if (valid) {
#pragma unroll
        for (int j = 0; j < 4; ++j)
          v[j] = *(const v4f*)(xim + (size_t)(cg * 4 + j) * 3136 + ih * 56 + w4 * 4);
      }
#pragma unroll
      for (int e = 0; e < 4; ++e) {
        int dw = 0;
        if (valid) {
#pragma unroll
          for (int j = 0; j < 4; ++j) {
            float tq;
            {
#pragma clang fp contract(off)
              tq = v[j][e] * sa - zp;   // match ref: mul then sub, no fma
            }
            float qf = rintf(tq);       // half-to-even, like jnp.round
            qf = fminf(fmaxf(qf, 0.0f), 255.0f);
            const int bb = ((int)qf - 128) & 255;
            dw |= bb << (8 * j);
          }
        }
        const int c = w4 * 4 + 1 + e;   // stored column (incl. pad col 0)
        const int t = (c >> 1) & 3;     // unit swizzle
        ((int*)lds)[(row * 58 + c) * 16 + (((cg >> 2) ^ t) << 2) + (cg & 3)] = dw;
      }
    } else {                            // col pads: col 0 and col 57, 6 rows
      const int z = idx - 1344;         // 0..191
      const int loc = z >> 4, d = z & 15;
      const int row = loc >> 1, side = loc & 1;
      ((int*)lds)[(row * 58 + side * 57) * 16 + d] = 0;
    }
  }
  __syncthreads();

  // ---- phase 2: MFMA implicit GEMM ----
  const int lane = tid & 63;
  const int wv = tid >> 6;
  const int phalf = wv & 1;             // px offset 112*phalf
  const int ogp = wv >> 1;              // och 32*ogp
  const int ln = lane & 15;
  const int kg = lane >> 4;             // k-group: bytes kg*16..kg*16+15
  const int oa = ogp * 32 + ln;         // first och; second is oa+16

  // B fragments for both och groups: B[n=ln][k = kg*16 + j] per tap
  const signed char* wba = w8 + (size_t)oa * 576 + kg * 16;
  v4i Ba[9], Bb[9];
#pragma unroll
  for (int t = 0; t < 9; ++t) {
    Ba[t] = *(const v4i*)(wba + t * 64);
    Bb[t] = *(const v4i*)(wba + 9216 + t * 64);   // (oa+16)*576
  }

  const float sw = sw_p[0];
  const float rden = 1.0f / (sw * sa);
  const float boa = bias[oa], bob = bias[oa + 16];
  const float cFa = corr_tab[oa];       // interior (case 0) corrections (L2)
  const float cFb = corr_tab[oa + 16];
  float* const outa = out + (size_t)(n * 64 + oa) * 3136 + h0 * 56;
  float* const outb = outa + 16 * 3136;

#pragma unroll 1
  for (int t = 0; t < 7; ++t) {
    const int pb = phalf * 112 + t * 16;          // block-relative px tile base
    const int pa = pb + ln;                       // this lane's A-row px (0..223)
    const int hr = (pa * 9363) >> 19;             // pa / 56 (exact)
    const int wc = pa - hr * 56;
    // per-kw column byte offsets incl. unit swizzle (c = wc+kw, 0..57)
    int coff[3];
#pragma unroll
    for (int kw = 0; kw < 3; ++kw) {
      const int c = wc + kw;
      coff[kw] = c * 64 + ((kg ^ ((c >> 1) & 3)) << 4);
    }
    const signed char* rowb = lds + hr * 3712;    // 58*64 per qa row
    v4i acca = {0, 0, 0, 0}, accb = {0, 0, 0, 0};
#pragma unroll
    for (int kh = 0; kh < 3; ++kh) {
#pragma unroll
      for (int kw = 0; kw < 3; ++kw) {
        const v4i A = *(const v4i*)(rowb + kh * 3712 + coff[kw]);
        acca = __builtin_amdgcn_mfma_i32_16x16x64_i8(A, Ba[kh * 3 + kw], acca, 0, 0, 0);
        accb = __builtin_amdgcn_mfma_i32_16x16x64_i8(A, Bb[kh * 3 + kw], accb, 0, 0, 0);
      }
    }
    // epilogue: C/D row(px) = kg*4 + reg, col(och) = ln
    const int pxb = pb + kg * 4;
    float ta[4], tb[4];
#pragma unroll
    for (int e = 0; e < 4; ++e) {
      const int px = pxb + e;
      const int hh = (px * 9363) >> 19;
      const int ww = px - hh * 56;
      const int hg = h0 + hh;
      float ca = cFa, cb = cFb;
      if ((hg == 0) | (hg == 55) | (ww == 0) | (ww == 55)) {   // rare border
        const int vcase = (hg == 0) ? 1 : ((hg == 55) ? 2 : 0);
        const int hcase = (ww == 0) ? 1 : ((ww == 55) ? 2 : 0);
        const int cidx = (vcase * 3 + hcase) * 64;
        ca = corr_tab[cidx + oa];
        cb = corr_tab[cidx + oa + 16];
      }
      ta[e] = ((float)acca[e] + ca) * rden + boa;
      tb[e] = ((float)accb[e] + cb) * rden + bob;
    }
    *(float4*)(outa + pxb) = make_float4(ta[0], ta[1], ta[2], ta[3]);
    *(float4*)(outb + pxb) = make_float4(tb[0], tb[1], tb[2], tb[3]);
  }
}

extern "C" void kernel_launch(void* const* d_in, const int* in_sizes, int n_in,
                              void* d_out, int out_size, void* d_ws, size_t ws_size,
                              hipStream_t stream) {
  const float* x    = (const float*)d_in[0];
  const float* wt   = (const float*)d_in[1];
  const float* bias = (const float*)d_in[2];
  const float* sa   = (const float*)d_in[3];
  const float* sw   = (const float*)d_in[4];
  const float* zp   = (const float*)d_in[5];
  float* out = (float*)d_out;

  char* ws = (char*)d_ws;
  signed char* w8 = (signed char*)ws;                 // 36,864 B
  float* corr_tab = (float*)(ws + 36864);             // 2,304 B

  prep_wq<<<64, 64, 0, stream>>>(wt, sw, zp, w8, corr_tab);
  conv_fused<<<896, 256, 0, stream>>>(x, w8, corr_tab, bias, sa, sw, zp, out);
}